// Round 9
// baseline (218.384 us; speedup 1.0000x reference)
//
#include <hip/hip_runtime.h>
#include <math.h>

#define NB 16
#define NA 64
#define NPAIR 2016
#define PSEL 256
#define NEL 128
// ws byte offsets (256-aligned)
#define WS_SUMW   0                      // [16] f32
#define WS_SELJ   2048                   // [4096] i32
#define WS_SELK   (WS_SELJ + 16384)
#define WS_SCAL   (WS_SELK + 16384)      // [4096][8] f32 (r0j,r0k,rjk,cos,w,zj,zk,-)
#define WS_AE     (WS_SCAL + 131072)     // [128][128] f32 (incl pb0)
#define WS_GG     (WS_AE + 65536)        // [4096][64] f32
#define WS_ZRJ    (WS_GG + 1048576)      // [91][128] f32
#define WS_ZRK    (WS_ZRJ + 47104)
#define WS_AGG    (WS_ZRK + 47104)       // [16][128][64] f32
#define WS_W1F    (WS_AGG + 524288)      // bf16 frag pw1, 32KB
#define WS_W2F    (WS_W1F + 32768)       // bf16 frag pw2, 16KB
#define WS_G0F    (WS_W2F + 16384)      // bf16 frag gw0 (K pad 384), 192KB
#define WS_G1F    (WS_G0F + 196608)      // bf16 frag gw1, 128KB
#define WS_G2F    (WS_G1F + 131072)      // bf16 frag gw2, 32KB

// prep index-space bounds (kA blocks 0..1466; k1-select blocks 1467..1482)
#define PREP_BLOCKS 1467
#define IDX_W1F  16384
#define IDX_W2F  24576
#define IDX_G0F  122880
#define IDX_G1F  188416
#define IDX_G2F  204800
#define IDX_AE   221184
#define IDX_ZRJ  232832
#define IDX_ZRK  244480
#define IDX_AGG  375552

typedef short v8s __attribute__((ext_vector_type(8)));
typedef float v4f __attribute__((ext_vector_type(4)));

__device__ __forceinline__ float siluf_fast(float x) {
  float e = __expf(-x);
  return x * __builtin_amdgcn_rcpf(1.0f + e);
}
__device__ __forceinline__ unsigned short f2bf(float f) {
  unsigned int u = __float_as_uint(f);
  return (unsigned short)((u + 0x7fffu + ((u >> 16) & 1u)) >> 16);
}
// single-instruction packed f32->bf16 (RNE), low half = fa, high half = fb
__device__ __forceinline__ unsigned int cvt_pk_bf16(float fa, float fb) {
  unsigned int r;
  asm("v_cvt_pk_bf16_f32 %0, %1, %2" : "=v"(r) : "v"(fa), "v"(fb));
  return r;
}
__device__ __forceinline__ float cutf(float r) {
  return (r <= 6.0f) ? (0.5f * (cosf((3.14159265358979323846f * r) / 6.0f) + 1.0f)) : 0.0f;
}
__device__ __forceinline__ float rbff(float r, int i) {
  float rc = fminf(r, 6.0f);
  float c = (float)i * (6.0f / 31.0f);
  float d = rc - c;
  return expf(-26.694445f * d * d);
}
__device__ __forceinline__ void pair_jk(int p, int& j, int& k) {
  int jj = (int)((127.0 - sqrt(16129.0 - 8.0 * (double)p)) * 0.5);
  if (jj < 0) jj = 0;
  if (jj > 62) jj = 62;
  while (jj < 62 && (63 * (jj + 1) - ((jj + 1) * jj) / 2) <= p) jj++;
  while (jj > 0 && (63 * jj - (jj * (jj - 1)) / 2) > p) jj--;
  j = jj;
  k = p - (63 * jj - (jj * (jj - 1)) / 2) + jj + 1;
}

// ---- fused: weight-frag prep + Ae/zrow tables + AGG zero (blocks < PREP_BLOCKS)
//      + per-batch pair scoring / stable top-256 radix select (last 16 blocks)
__global__ __launch_bounds__(256) void kA(
    const int* __restrict__ z, const float* __restrict__ ef,
    const float* __restrict__ pos,
    const float* __restrict__ pw0, const float* __restrict__ pb0,
    const float* __restrict__ pw1, const float* __restrict__ pw2,
    const float* __restrict__ gw0, const float* __restrict__ gw1,
    const float* __restrict__ gw2, const float* __restrict__ zemb, char* ws) {
  __shared__ float px[64], py[64], pz[64], rr[64];
  __shared__ int hist[256], scan[256];
  __shared__ unsigned long long selk[256];
  __shared__ float wred[256];
  __shared__ unsigned long long s_pref, s_kstar;
  __shared__ int s_K, s_done, s_digit, s_exc, s_cnt;
  int blk = blockIdx.x, t = threadIdx.x;

  if (blk < PREP_BLOCKS) {
    int idx = blk * 256 + t;
    if (idx < IDX_W1F) {  // W1F: 128x128, NKK=4, A[n][k] frag order
      int j = idx & 7, l = (idx >> 3) & 63, t2 = idx >> 9;
      int kk = t2 & 3, nt = t2 >> 2;
      int n = 16 * nt + (l & 15), k = 32 * kk + (l >> 4) * 8 + j;
      ((unsigned short*)(ws + WS_W1F))[idx] = f2bf(pw1[k * 128 + n]);
    } else if (idx < IDX_W2F) {  // W2F: 128x64, NKK=4
      int id = idx - IDX_W1F;
      int j = id & 7, l = (id >> 3) & 63, t2 = id >> 9;
      int kk = t2 & 3, nt = t2 >> 2;
      int n = 16 * nt + (l & 15), k = 32 * kk + (l >> 4) * 8 + j;
      ((unsigned short*)(ws + WS_W2F))[id] = f2bf(pw2[k * 64 + n]);
    } else if (idx < IDX_G0F) {  // G0F: 353(->384)x256, NKK=12
      int id = idx - IDX_W2F;
      int j = id & 7, l = (id >> 3) & 63, t2 = id >> 9;
      int kk = t2 % 12, nt = t2 / 12;
      int n = 16 * nt + (l & 15), k = 32 * kk + (l >> 4) * 8 + j;
      float v = (k < 353) ? gw0[k * 256 + n] : 0.0f;
      ((unsigned short*)(ws + WS_G0F))[id] = f2bf(v);
    } else if (idx < IDX_G1F) {  // G1F: 256x256, NKK=8
      int id = idx - IDX_G0F;
      int j = id & 7, l = (id >> 3) & 63, t2 = id >> 9;
      int kk = t2 & 7, nt = t2 >> 3;
      int n = 16 * nt + (l & 15), k = 32 * kk + (l >> 4) * 8 + j;
      ((unsigned short*)(ws + WS_G1F))[id] = f2bf(gw1[k * 256 + n]);
    } else if (idx < IDX_G2F) {  // G2F: 256x64, NKK=8
      int id = idx - IDX_G1F;
      int j = id & 7, l = (id >> 3) & 63, t2 = id >> 9;
      int kk = t2 & 7, nt = t2 >> 3;
      int n = 16 * nt + (l & 15), k = 32 * kk + (l >> 4) * 8 + j;
      ((unsigned short*)(ws + WS_G2F))[id] = f2bf(gw2[k * 64 + n]);
    } else if (idx < IDX_AE) {  // Ae[e][d] = ef[e]@pw0[64:96] + pb0[d]
      int id = idx - IDX_G2F;
      int e = id >> 7, d = id & 127;
      float a = pb0[d];
      for (int i = 0; i < 32; i++) a += ef[e * 32 + i] * pw0[(64 + i) * 128 + d];
      ((float*)(ws + WS_AE))[e * 128 + d] = a;
    } else if (idx < IDX_ZRJ) {  // zrowJ[zv][d] = z_emb[zv]@pw0[0:32]
      int id = idx - IDX_AE;
      int zv = id >> 7, d = id & 127;
      float a = 0.0f;
      for (int i = 0; i < 32; i++) a += zemb[zv * 32 + i] * pw0[i * 128 + d];
      ((float*)(ws + WS_ZRJ))[id] = a;
    } else if (idx < IDX_ZRK) {  // zrowK[zv][d] = z_emb[zv]@pw0[32:64]
      int id = idx - IDX_ZRJ;
      int zv = id >> 7, d = id & 127;
      float a = 0.0f;
      for (int i = 0; i < 32; i++) a += zemb[zv * 32 + i] * pw0[(32 + i) * 128 + d];
      ((float*)(ws + WS_ZRK))[id] = a;
    } else if (idx < IDX_AGG) {  // zero AGG
      ((float*)(ws + WS_AGG))[idx - IDX_ZRK] = 0.0f;
    }
    return;
  }

  // ---- pair scoring + exact stable top-256 via 8-bit radix select on
  // 64-bit keys (score_bits<<32 | pair_idx); set identical to stable argsort.
  // R7: inclusive scan via per-wave __shfl_up (1 barrier) instead of the
  // 16-barrier LDS ladder — these 16 blocks run nearly solo on the GPU.
  {
#pragma clang fp contract(off)
    int b = blk - PREP_BLOCKS;
    int is64 = (z[1] == 0) ? 1 : 0;
    if (t < 64) {
      px[t] = pos[(b * 64 + t) * 3 + 0];
      py[t] = pos[(b * 64 + t) * 3 + 1];
      pz[t] = pos[(b * 64 + t) * 3 + 2];
    }
    if (t == 0) { s_pref = 0; s_K = PSEL; s_done = 0; s_cnt = 0; }
    __syncthreads();
    if (t < 64) {
      float dx = px[t] - px[0], dy = py[t] - py[0], dz = pz[t] - pz[0];
      rr[t] = sqrtf((dx * dx + dy * dy) + dz * dz);
    }
    __syncthreads();
    unsigned long long keys[8];
#pragma unroll
    for (int ii = 0; ii < 8; ii++) {
      int p = t + 256 * ii;
      unsigned long long key = 0xFFFFFFFFFFFFFFFFull;
      if (p < NPAIR) {
        int j, k;
        pair_jk(p, j, k);
        bool vj = (j != 0) && (rr[j] <= 6.0f);
        bool vk = (rr[k] <= 6.0f);
        unsigned int sb = 0x7f800000u;
        if (vj && vk) {
          float dx = px[k] - px[j], dy = py[k] - py[j], dz = pz[k] - pz[j];
          float rjk = sqrtf((dx * dx + dy * dy) + dz * dz);
          float score = (rr[j] + rr[k]) + 0.5f * rjk;
          sb = __float_as_uint(score);
        }
        key = (((unsigned long long)sb) << 32) | (unsigned int)p;
      }
      keys[ii] = key;
    }
    for (int shift = 56; shift >= 0; shift -= 8) {
      if (s_done) break;
      hist[t] = 0;
      __syncthreads();
      unsigned long long hiMask = (shift == 56) ? 0ull : (~0ull << (shift + 8));
      unsigned long long pref = s_pref;
      int K = s_K;
#pragma unroll
      for (int ii = 0; ii < 8; ii++) {
        if ((keys[ii] & hiMask) == pref)
          atomicAdd(&hist[(int)((keys[ii] >> shift) & 255)], 1);
      }
      __syncthreads();
      // inclusive scan of hist[0..255] across bin index t: wave-shfl + combine
      int v = hist[t];
#pragma unroll
      for (int off = 1; off < 64; off <<= 1) {
        int nb = __shfl_up(v, off);
        if ((t & 63) >= off) v += nb;
      }
      if ((t & 63) == 63) scan[t >> 6] = v;  // wave totals in scan[0..3]
      __syncthreads();
      int addw = 0;
#pragma unroll
      for (int ww = 0; ww < 3; ww++)
        if (ww < (t >> 6)) addw += scan[ww];
      int inc = v + addw, exc = inc - hist[t];
      if (exc < K && K <= inc) { s_digit = t; s_exc = exc; }
      __syncthreads();
      int d = s_digit, exc2 = s_exc, cnt = hist[d];
      unsigned long long npref = pref | ((unsigned long long)d << shift);
      if (cnt == 1) {
        unsigned long long inclMask = hiMask | (255ull << shift);
#pragma unroll
        for (int ii = 0; ii < 8; ii++)
          if ((keys[ii] & inclMask) == npref) s_kstar = keys[ii];
        if (t == 0) s_done = 1;
      } else if (shift == 0) {
        if (t == 0) { s_kstar = npref; s_done = 1; }
      } else {
        if (t == 0) { s_pref = npref; s_K = K - exc2; }
      }
      __syncthreads();
    }
    unsigned long long kstar = s_kstar;
#pragma unroll
    for (int ii = 0; ii < 8; ii++) {
      if (keys[ii] <= kstar) {
        int slot = atomicAdd(&s_cnt, 1);
        selk[slot] = keys[ii];
      }
    }
    __syncthreads();
    float myw = 0.0f;
    {
      unsigned long long key = selk[t];
      unsigned int sb = (unsigned int)(key >> 32);
      int p = (int)(key & 0xFFFFFFFFu);
      bool pv = (sb < 0x7f800000u);
      int j = 0, k = 0;
      if (pv) pair_jk(p, j, k);
      float r0j = rr[j], r0k = rr[k];
      float vjx = px[j] - px[0], vjy = py[j] - py[0], vjz = pz[j] - pz[0];
      float vkx = px[k] - px[0], vky = py[k] - py[0], vkz = pz[k] - pz[0];
      float dx = px[k] - px[j], dy = py[k] - py[j], dz = pz[k] - pz[j];
      float rjk = sqrtf((dx * dx + dy * dy) + dz * dz);
      float ij = 1.0f / fmaxf(r0j, 1e-8f);
      float ik = 1.0f / fmaxf(r0k, 1e-8f);
      float cs = (vjx * vkx + vjy * vky + vjz * vkz) * ij * ik;
      cs = fminf(1.0f, fmaxf(-1.0f, cs));
      float w = pv ? (cutf(r0j) * cutf(r0k) * cutf(rjk)) : 0.0f;
      int zj = is64 ? z[(b * 64 + j) * 2] : z[b * 64 + j];
      int zk = is64 ? z[(b * 64 + k) * 2] : z[b * 64 + k];
      int* selJ = (int*)(ws + WS_SELJ);
      int* selK = (int*)(ws + WS_SELK);
      float* scal = (float*)(ws + WS_SCAL);
      selJ[b * PSEL + t] = j;
      selK[b * PSEL + t] = k;
      float* s = &scal[(b * PSEL + t) * 8];
      s[0] = r0j; s[1] = r0k; s[2] = rjk; s[3] = cs; s[4] = w;
      ((int*)s)[5] = zj; ((int*)s)[6] = zk;
      myw = w;
    }
    wred[t] = myw;
    __syncthreads();
    for (int s2 = 128; s2 > 0; s2 >>= 1) {
      if (t < s2) wred[t] += wred[t + s2];
      __syncthreads();
    }
    if (t == 0) ((float*)(ws + WS_SUMW))[b] = fmaxf(wred[0], 1e-8f);
  }
}

// geom MLP via bf16 MFMA: 353(pad384)->256->256->64, folds w/sumw into gg.
// R6: 1024 threads/block (16 waves/CU = 50% occupancy ceiling vs prior 12.5%).
// Each wave owns one 16-col N-tile of L1/L2 (gnt = w); L3 uses waves 0-3.
#define LP3 392
#define LQ3 264
__global__ __launch_bounds__(1024) void k3_geom(const float* __restrict__ h,
    const float* __restrict__ gb0, const float* __restrict__ gb1,
    const float* __restrict__ gb2, char* ws) {
  int blk = blockIdx.x;
  int b = blk >> 4, p0 = (blk & 15) * 16;
  int t = threadIdx.x;
  int lane = t & 63, w = t >> 6;  // w in [0,16)
  int q = lane >> 4, m4 = lane & 15;
  const int* selJ = (const int*)(ws + WS_SELJ);
  const int* selK = (const int*)(ws + WS_SELK);
  const float* scal = (const float*)(ws + WS_SCAL);
  const float* sumw = (const float*)(ws + WS_SUMW);
  float* gg = (float*)(ws + WS_GG);
  const unsigned short* G0F = (const unsigned short*)(ws + WS_G0F);
  const unsigned short* G1F = (const unsigned short*)(ws + WS_G1F);
  const unsigned short* G2F = (const unsigned short*)(ws + WS_G2F);
  __shared__ __align__(16) unsigned short xs[16 * LP3];
  __shared__ __align__(16) unsigned short x1s[16 * LQ3];
  __shared__ __align__(16) unsigned short x2s[16 * LQ3];
  const v4f z4 = {0.f, 0.f, 0.f, 0.f};
  {
    int row = t & 15, fs = t >> 4;  // fs in [0,64)
    int p = p0 + row;
    int j = selJ[b * PSEL + p], k = selK[b * PSEL + p];
    const float* s = &scal[(b * PSEL + p) * 8];
    float r0j = s[0], r0k = s[1], rjk = s[2], cs = s[3];
    for (int f = fs; f < 384; f += 64) {
      float v;
      if (f < 128) v = h[(b * 64 + j) * 128 + f];
      else if (f < 256) v = h[(b * 64 + k) * 128 + (f - 128)];
      else if (f < 288) v = rbff(r0j, f - 256);
      else if (f < 320) v = rbff(r0k, f - 288);
      else if (f < 352) v = rbff(rjk, f - 320);
      else if (f == 352) v = cs;
      else v = 0.0f;
      xs[row * LP3 + f] = f2bf(v);
    }
  }
  __syncthreads();
  {  // L1: out 16x256, K=384; wave w computes cols [16w, 16w+16)
    v4f acc = z4;
    for (int kk = 0; kk < 12; kk++) {
      v8s bf = *(const v8s*)&xs[m4 * LP3 + 32 * kk + 8 * q];
      v8s wf = *(const v8s*)&G0F[((w * 12 + kk) * 64 + lane) * 8];
      acc = __builtin_amdgcn_mfma_f32_16x16x32_bf16(wf, bf, acc, 0, 0, 0);
    }
    int n0 = 16 * w + 4 * q;
    float4 bias = *(const float4*)&gb0[n0];
    uint2 o;
    o.x = cvt_pk_bf16(siluf_fast(acc[0] + bias.x), siluf_fast(acc[1] + bias.y));
    o.y = cvt_pk_bf16(siluf_fast(acc[2] + bias.z), siluf_fast(acc[3] + bias.w));
    *(uint2*)&x1s[m4 * LQ3 + n0] = o;
  }
  __syncthreads();
  {  // L2: out 16x256, K=256
    v4f acc = z4;
    for (int kk = 0; kk < 8; kk++) {
      v8s bf = *(const v8s*)&x1s[m4 * LQ3 + 32 * kk + 8 * q];
      v8s wf = *(const v8s*)&G1F[((w * 8 + kk) * 64 + lane) * 8];
      acc = __builtin_amdgcn_mfma_f32_16x16x32_bf16(wf, bf, acc, 0, 0, 0);
    }
    int n0 = 16 * w + 4 * q;
    float4 bias = *(const float4*)&gb1[n0];
    uint2 o;
    o.x = cvt_pk_bf16(siluf_fast(acc[0] + bias.x), siluf_fast(acc[1] + bias.y));
    o.y = cvt_pk_bf16(siluf_fast(acc[2] + bias.z), siluf_fast(acc[3] + bias.w));
    *(uint2*)&x2s[m4 * LQ3 + n0] = o;
  }
  __syncthreads();
  if (w < 4) {  // L3: out 16x64, K=256, linear + fold w/norm
    v4f acc = z4;
    for (int kk = 0; kk < 8; kk++) {
      v8s bf = *(const v8s*)&x2s[m4 * LQ3 + 32 * kk + 8 * q];
      v8s wf = *(const v8s*)&G2F[((w * 8 + kk) * 64 + lane) * 8];
      acc = __builtin_amdgcn_mfma_f32_16x16x32_bf16(wf, bf, acc, 0, 0, 0);
    }
    int p = p0 + m4;
    float wp = scal[(b * PSEL + p) * 8 + 4];
    float s2 = wp / sumw[b];
    int n0 = 16 * w + 4 * q;
    float4 bias = *(const float4*)&gb2[n0];
    float4 o;
    o.x = (acc[0] + bias.x) * s2;
    o.y = (acc[1] + bias.y) * s2;
    o.z = (acc[2] + bias.z) * s2;
    o.w = (acc[3] + bias.w) * s2;
    *(float4*)&gg[(b * PSEL + p) * 64 + n0] = o;
  }
}

// fused elem MLP via bf16 MFMA; A0 reconstructed on the fly from zrow tables.
// R8 DIAGNOSTIC: split into two half-dispatches (et0 = 0 / 8) so each half
// (~33us) drops below kA/k3/k5 in the top-5 window — reveals the 140us
// "others" bucket. Body is byte-identical to the measured R7 kernel.
#define LP 136
__global__ __launch_bounds__(256, 4) void k4_elem(
    const float* __restrict__ pb1, const float* __restrict__ pb2, char* ws,
    int et0) {
  int et = et0 + blockIdx.x, b = blockIdx.y, pc = blockIdx.z;  // et<16, b<16, pc<8
  int t = threadIdx.x;
  int lane = t & 63, w = t >> 6;
  int q = lane >> 4, m4 = lane & 15;
  const float* Ae = (const float*)(ws + WS_AE);
  const float* gg = (const float*)(ws + WS_GG);
  const float* zrJ = (const float*)(ws + WS_ZRJ);
  const float* zrK = (const float*)(ws + WS_ZRK);
  const unsigned short* W1F = (const unsigned short*)(ws + WS_W1F);
  const unsigned short* W2F = (const unsigned short*)(ws + WS_W2F);
  float* agg = (float*)(ws + WS_AGG);
  __shared__ __align__(16) unsigned short x0s[64 * LP];
  __shared__ __align__(16) unsigned short x1s[64 * LP];
  int e0 = et * 8;

  v8s w1f[2][4], w2f[4];
#pragma unroll
  for (int ct = 0; ct < 2; ct++)
#pragma unroll
    for (int kk = 0; kk < 4; kk++)
      w1f[ct][kk] = *(const v8s*)&W1F[(((2 * w + ct) * 4 + kk) * 64 + lane) * 8];
#pragma unroll
  for (int kk = 0; kk < 4; kk++)
    w2f[kk] = *(const v8s*)&W2F[(((w) * 4 + kk) * 64 + lane) * 8];
  float4 b1v[2];
  b1v[0] = *(const float4*)&pb1[32 * w + 4 * q];
  b1v[1] = *(const float4*)&pb1[32 * w + 16 + 4 * q];
  float4 b2v = *(const float4*)&pb2[16 * w + 4 * q];

  // phase-A constants: thread t covers (pl = t>>5, k0 = (t&31)*4)
  int pl = t >> 5, k0 = (t & 31) * 4;
  const int* sI = (const int*)(ws + WS_SCAL) + (b * PSEL + pc * 32 + pl) * 8;
  const float* aep = Ae + e0 * 128 + k0;
  unsigned short* xw = &x0s[pl * LP + k0];
  const float* ggp = gg + (b * PSEL + pc * 32 + (lane & 7)) * 64 + 16 * w + 4 * q;

  v4f aggR[4];
  v4f gvs;
  const v4f z4 = {0.f, 0.f, 0.f, 0.f};
#pragma unroll
  for (int mt = 0; mt < 4; mt++) aggR[mt] = z4;
  gvs = z4;

  for (int g2 = 0; g2 < 4; g2++) {
    // phase A: x0s[8it+pl][k0..k0+3] = silu(zrJ[zj]+zrK[zk]+Ae[e0+it]), bf16
    int zj = sI[5], zk = sI[6];
    sI += 64;
    float4 aj = *(const float4*)&zrJ[zj * 128 + k0];
    float4 ak = *(const float4*)&zrK[zk * 128 + k0];
    float4 a0v;
    a0v.x = aj.x + ak.x; a0v.y = aj.y + ak.y;
    a0v.z = aj.z + ak.z; a0v.w = aj.w + ak.w;
#pragma unroll
    for (int it = 0; it < 8; it++) {
      float4 aev = *(const float4*)(aep + it * 128);
      uint2 o;
      o.x = cvt_pk_bf16(siluf_fast(a0v.x + aev.x), siluf_fast(a0v.y + aev.y));
      o.y = cvt_pk_bf16(siluf_fast(a0v.z + aev.z), siluf_fast(a0v.w + aev.w));
      *(uint2*)(xw + it * 8 * LP) = o;
    }
    __syncthreads();  // (1) x0 visible; also: all L2-reads of prev iter done
    v4f acc1[4][2];
#pragma unroll
    for (int mt = 0; mt < 4; mt++) { acc1[mt][0] = z4; acc1[mt][1] = z4; }
#pragma unroll
    for (int kk = 0; kk < 4; kk++) {
#pragma unroll
      for (int mt = 0; mt < 4; mt++) {
        v8s bf = *(const v8s*)&x0s[(16 * mt + m4) * LP + 32 * kk + 8 * q];
        acc1[mt][0] = __builtin_amdgcn_mfma_f32_16x16x32_bf16(w1f[0][kk], bf, acc1[mt][0], 0, 0, 0);
        acc1[mt][1] = __builtin_amdgcn_mfma_f32_16x16x32_bf16(w1f[1][kk], bf, acc1[mt][1], 0, 0, 0);
      }
    }
    // x1 writes (no barrier needed: prev-iter L2 reads of x1s ordered before sync (1))
#pragma unroll
    for (int mt = 0; mt < 4; mt++) {
#pragma unroll
      for (int ct = 0; ct < 2; ct++) {
        float4 bias = b1v[ct];
        uint2 o;
        o.x = cvt_pk_bf16(siluf_fast(acc1[mt][ct][0] + bias.x), siluf_fast(acc1[mt][ct][1] + bias.y));
        o.y = cvt_pk_bf16(siluf_fast(acc1[mt][ct][2] + bias.z), siluf_fast(acc1[mt][ct][3] + bias.w));
        int n0 = 32 * w + 16 * ct + 4 * q;
        *(uint2*)&x1s[(16 * mt + m4) * LP + n0] = o;
      }
    }
    __syncthreads();  // (2) x1 visible; also: all L1-reads of x0s done
    v4f acc2[4];
#pragma unroll
    for (int mt = 0; mt < 4; mt++) acc2[mt] = z4;
#pragma unroll
    for (int kk = 0; kk < 4; kk++) {
#pragma unroll
      for (int mt = 0; mt < 4; mt++) {
        v8s bf = *(const v8s*)&x1s[(16 * mt + m4) * LP + 32 * kk + 8 * q];
        acc2[mt] = __builtin_amdgcn_mfma_f32_16x16x32_bf16(w2f[kk], bf, acc2[mt], 0, 0, 0);
      }
    }
    float4 gv = *(const float4*)ggp;
    ggp += 512;
    // bias folded out: sum gv separately, add b2v * (sum gv) after the loop
    gvs[0] += gv.x; gvs[1] += gv.y; gvs[2] += gv.z; gvs[3] += gv.w;
#pragma unroll
    for (int mt = 0; mt < 4; mt++) {
      aggR[mt][0] += gv.x * acc2[mt][0];
      aggR[mt][1] += gv.y * acc2[mt][1];
      aggR[mt][2] += gv.z * acc2[mt][2];
      aggR[mt][3] += gv.w * acc2[mt][3];
    }
  }
#pragma unroll
  for (int mt = 0; mt < 4; mt++) {
    aggR[mt][0] += gvs[0] * b2v.x;
    aggR[mt][1] += gvs[1] * b2v.y;
    aggR[mt][2] += gvs[2] * b2v.z;
    aggR[mt][3] += gvs[3] * b2v.w;
  }
#pragma unroll
  for (int mt = 0; mt < 4; mt++) {
#pragma unroll
    for (int r = 0; r < 4; r++) {
      float v = aggR[mt][r];
      v += __shfl_xor(v, 1);
      v += __shfl_xor(v, 2);
      v += __shfl_xor(v, 4);
      if ((lane & 7) == 0) {
        int e = 2 * mt + ((lane >> 3) & 1);
        int n = 16 * w + 4 * q + r;
        atomicAdd(&agg[(b * NEL + e0 + e) * 64 + n], v);
      }
    }
  }
}

// output MLP 64->256 silu ->128
__global__ __launch_bounds__(256) void k5_out(
    const float* __restrict__ ow0, const float* __restrict__ ob0,
    const float* __restrict__ ow1, const float* __restrict__ ob1,
    const char* ws, float* __restrict__ out) {
  int row0 = blockIdx.x * 16;
  int t = threadIdx.x;
  const float* agg = (const float*)(ws + WS_AGG);
  __shared__ float xT[64][16];
  __shared__ float x1T[256][16];
  {
    int row = t & 15, fs = t >> 4;
    for (int f = fs; f < 64; f += 16) xT[f][row] = agg[(row0 + row) * 64 + f];
  }
  __syncthreads();
  {
    int r0 = (t & 3) * 4, c0 = (t >> 2) * 4;
    float acc[4][4] = {};
    for (int k2 = 0; k2 < 64; k2++) {
      float4 xv = *(const float4*)&xT[k2][r0];
      float4 wv = *(const float4*)&ow0[k2 * 256 + c0];
      float xs2[4] = {xv.x, xv.y, xv.z, xv.w};
      float wss[4] = {wv.x, wv.y, wv.z, wv.w};
#pragma unroll
      for (int i = 0; i < 4; i++)
#pragma unroll
        for (int j2 = 0; j2 < 4; j2++) acc[i][j2] += xs2[i] * wss[j2];
    }
#pragma unroll
    for (int jj = 0; jj < 4; jj++) {
      float bias = ob0[c0 + jj];
#pragma unroll
      for (int i = 0; i < 4; i++) x1T[c0 + jj][r0 + i] = siluf_fast(acc[i][jj] + bias);
    }
  }
  __syncthreads();
  {
    int r0 = (t & 3) * 4, c0 = (t >> 2) * 2;
    float acc[4][2] = {};
    for (int k2 = 0; k2 < 256; k2++) {
      float4 xv = *(const float4*)&x1T[k2][r0];
      float2 wv = *(const float2*)&ow1[k2 * 128 + c0];
      float xs2[4] = {xv.x, xv.y, xv.z, xv.w};
#pragma unroll
      for (int i = 0; i < 4; i++) {
        acc[i][0] += xs2[i] * wv.x;
        acc[i][1] += xs2[i] * wv.y;
      }
    }
#pragma unroll
    for (int i = 0; i < 4; i++)
#pragma unroll
      for (int j2 = 0; j2 < 2; j2++)
        out[(row0 + r0 + i) * 128 + c0 + j2] = acc[i][j2] + ob1[c0 + j2];
  }
}

extern "C" void kernel_launch(void* const* d_in, const int* in_sizes, int n_in,
                              void* d_out, int out_size, void* d_ws, size_t ws_size,
                              hipStream_t stream) {
  const float* h     = (const float*)d_in[0];
  const int*   z     = (const int*)d_in[1];
  const float* pos   = (const float*)d_in[2];
  const float* efeat = (const float*)d_in[4];
  const float* zemb  = (const float*)d_in[5];
  const float* pw0 = (const float*)d_in[6];
  const float* pb0 = (const float*)d_in[7];
  const float* pw1 = (const float*)d_in[8];
  const float* pb1 = (const float*)d_in[9];
  const float* pw2 = (const float*)d_in[10];
  const float* pb2 = (const float*)d_in[11];
  const float* gw0 = (const float*)d_in[12];
  const float* gb0 = (const float*)d_in[13];
  const float* gw1 = (const float*)d_in[14];
  const float* gb1 = (const float*)d_in[15];
  const float* gw2 = (const float*)d_in[16];
  const float* gb2 = (const float*)d_in[17];
  const float* ow0 = (const float*)d_in[18];
  const float* ob0 = (const float*)d_in[19];
  const float* ow1 = (const float*)d_in[20];
  const float* ob1 = (const float*)d_in[21];
  char* ws = (char*)d_ws;
  float* out = (float*)d_out;

  kA<<<PREP_BLOCKS + 16, 256, 0, stream>>>(z, efeat, pos, pw0, pb0, pw1, pw2,
                                           gw0, gw1, gw2, zemb, ws);
  k3_geom<<<256, 1024, 0, stream>>>(h, gb0, gb1, gb2, ws);
  k4_elem<<<dim3(8, 16, 8), 256, 0, stream>>>(pb1, pb2, ws, 0);
  k4_elem<<<dim3(8, 16, 8), 256, 0, stream>>>(pb1, pb2, ws, 8);
  k5_out<<<128, 256, 0, stream>>>(ow0, ob0, ow1, ob1, ws, out);
}

// Round 10
// 205.318 us; speedup vs baseline: 1.0636x; 1.0636x over previous
//
#include <hip/hip_runtime.h>
#include <math.h>

#define NB 16
#define NA 64
#define NPAIR 2016
#define PSEL 256
#define NEL 128
// ws byte offsets (256-aligned)
#define WS_SUMW   0                      // [16] f32
#define WS_SELJ   2048                   // [4096] i32
#define WS_SELK   (WS_SELJ + 16384)
#define WS_SCAL   (WS_SELK + 16384)      // [4096][8] f32 (r0j,r0k,rjk,cos,w,zj,zk,-)
#define WS_AE     (WS_SCAL + 131072)     // [128][128] f32 (incl pb0)
#define WS_GG     (WS_AE + 65536)        // [4096][64] f32
#define WS_ZRJ    (WS_GG + 1048576)      // [91][128] f32
#define WS_ZRK    (WS_ZRJ + 47104)
#define WS_AGG    (WS_ZRK + 47104)       // [16][128][64] f32
#define WS_W1F    (WS_AGG + 524288)      // bf16 frag pw1, 32KB
#define WS_W2F    (WS_W1F + 32768)       // bf16 frag pw2, 16KB
#define WS_G0F    (WS_W2F + 16384)      // bf16 frag gw0 (K pad 384), 192KB
#define WS_G1F    (WS_G0F + 196608)      // bf16 frag gw1, 128KB
#define WS_G2F    (WS_G1F + 131072)      // bf16 frag gw2, 32KB

// prep index-space bounds (kA blocks 0..1466; k1-select blocks 1467..1482)
#define PREP_BLOCKS 1467
#define IDX_W1F  16384
#define IDX_W2F  24576
#define IDX_G0F  122880
#define IDX_G1F  188416
#define IDX_G2F  204800
#define IDX_AE   221184
#define IDX_ZRJ  232832
#define IDX_ZRK  244480
#define IDX_AGG  375552

typedef short v8s __attribute__((ext_vector_type(8)));
typedef float v4f __attribute__((ext_vector_type(4)));

__device__ __forceinline__ float siluf_fast(float x) {
  float e = __expf(-x);
  return x * __builtin_amdgcn_rcpf(1.0f + e);
}
__device__ __forceinline__ unsigned short f2bf(float f) {
  unsigned int u = __float_as_uint(f);
  return (unsigned short)((u + 0x7fffu + ((u >> 16) & 1u)) >> 16);
}
// single-instruction packed f32->bf16 (RNE), low half = fa, high half = fb
__device__ __forceinline__ unsigned int cvt_pk_bf16(float fa, float fb) {
  unsigned int r;
  asm("v_cvt_pk_bf16_f32 %0, %1, %2" : "=v"(r) : "v"(fa), "v"(fb));
  return r;
}
__device__ __forceinline__ float cutf(float r) {
  return (r <= 6.0f) ? (0.5f * (cosf((3.14159265358979323846f * r) / 6.0f) + 1.0f)) : 0.0f;
}
__device__ __forceinline__ float rbff(float r, int i) {
  float rc = fminf(r, 6.0f);
  float c = (float)i * (6.0f / 31.0f);
  float d = rc - c;
  return expf(-26.694445f * d * d);
}
__device__ __forceinline__ void pair_jk(int p, int& j, int& k) {
  int jj = (int)((127.0 - sqrt(16129.0 - 8.0 * (double)p)) * 0.5);
  if (jj < 0) jj = 0;
  if (jj > 62) jj = 62;
  while (jj < 62 && (63 * (jj + 1) - ((jj + 1) * jj) / 2) <= p) jj++;
  while (jj > 0 && (63 * jj - (jj * (jj - 1)) / 2) > p) jj--;
  j = jj;
  k = p - (63 * jj - (jj * (jj - 1)) / 2) + jj + 1;
}

// ---- fused: weight-frag prep + Ae/zrow tables + AGG zero (blocks < PREP_BLOCKS)
//      + per-batch pair scoring / stable top-256 radix select (last 16 blocks)
__global__ __launch_bounds__(256) void kA(
    const int* __restrict__ z, const float* __restrict__ ef,
    const float* __restrict__ pos,
    const float* __restrict__ pw0, const float* __restrict__ pb0,
    const float* __restrict__ pw1, const float* __restrict__ pw2,
    const float* __restrict__ gw0, const float* __restrict__ gw1,
    const float* __restrict__ gw2, const float* __restrict__ zemb, char* ws) {
  __shared__ float px[64], py[64], pz[64], rr[64];
  __shared__ int hist[256], scan[256];
  __shared__ unsigned long long selk[256];
  __shared__ float wred[256];
  __shared__ unsigned long long s_pref, s_kstar;
  __shared__ int s_K, s_done, s_digit, s_exc, s_cnt;
  int blk = blockIdx.x, t = threadIdx.x;

  if (blk < PREP_BLOCKS) {
    int idx = blk * 256 + t;
    if (idx < IDX_W1F) {  // W1F: 128x128, NKK=4, A[n][k] frag order
      int j = idx & 7, l = (idx >> 3) & 63, t2 = idx >> 9;
      int kk = t2 & 3, nt = t2 >> 2;
      int n = 16 * nt + (l & 15), k = 32 * kk + (l >> 4) * 8 + j;
      ((unsigned short*)(ws + WS_W1F))[idx] = f2bf(pw1[k * 128 + n]);
    } else if (idx < IDX_W2F) {  // W2F: 128x64, NKK=4
      int id = idx - IDX_W1F;
      int j = id & 7, l = (id >> 3) & 63, t2 = id >> 9;
      int kk = t2 & 3, nt = t2 >> 2;
      int n = 16 * nt + (l & 15), k = 32 * kk + (l >> 4) * 8 + j;
      ((unsigned short*)(ws + WS_W2F))[id] = f2bf(pw2[k * 64 + n]);
    } else if (idx < IDX_G0F) {  // G0F: 353(->384)x256, NKK=12
      int id = idx - IDX_W2F;
      int j = id & 7, l = (id >> 3) & 63, t2 = id >> 9;
      int kk = t2 % 12, nt = t2 / 12;
      int n = 16 * nt + (l & 15), k = 32 * kk + (l >> 4) * 8 + j;
      float v = (k < 353) ? gw0[k * 256 + n] : 0.0f;
      ((unsigned short*)(ws + WS_G0F))[id] = f2bf(v);
    } else if (idx < IDX_G1F) {  // G1F: 256x256, NKK=8
      int id = idx - IDX_G0F;
      int j = id & 7, l = (id >> 3) & 63, t2 = id >> 9;
      int kk = t2 & 7, nt = t2 >> 3;
      int n = 16 * nt + (l & 15), k = 32 * kk + (l >> 4) * 8 + j;
      ((unsigned short*)(ws + WS_G1F))[id] = f2bf(gw1[k * 256 + n]);
    } else if (idx < IDX_G2F) {  // G2F: 256x64, NKK=8
      int id = idx - IDX_G1F;
      int j = id & 7, l = (id >> 3) & 63, t2 = id >> 9;
      int kk = t2 & 7, nt = t2 >> 3;
      int n = 16 * nt + (l & 15), k = 32 * kk + (l >> 4) * 8 + j;
      ((unsigned short*)(ws + WS_G2F))[id] = f2bf(gw2[k * 64 + n]);
    } else if (idx < IDX_AE) {  // Ae[e][d] = ef[e]@pw0[64:96] + pb0[d]
      int id = idx - IDX_G2F;
      int e = id >> 7, d = id & 127;
      float a = pb0[d];
      for (int i = 0; i < 32; i++) a += ef[e * 32 + i] * pw0[(64 + i) * 128 + d];
      ((float*)(ws + WS_AE))[e * 128 + d] = a;
    } else if (idx < IDX_ZRJ) {  // zrowJ[zv][d] = z_emb[zv]@pw0[0:32]
      int id = idx - IDX_AE;
      int zv = id >> 7, d = id & 127;
      float a = 0.0f;
      for (int i = 0; i < 32; i++) a += zemb[zv * 32 + i] * pw0[i * 128 + d];
      ((float*)(ws + WS_ZRJ))[id] = a;
    } else if (idx < IDX_ZRK) {  // zrowK[zv][d] = z_emb[zv]@pw0[32:64]
      int id = idx - IDX_ZRJ;
      int zv = id >> 7, d = id & 127;
      float a = 0.0f;
      for (int i = 0; i < 32; i++) a += zemb[zv * 32 + i] * pw0[(32 + i) * 128 + d];
      ((float*)(ws + WS_ZRK))[id] = a;
    } else if (idx < IDX_AGG) {  // zero AGG
      ((float*)(ws + WS_AGG))[idx - IDX_ZRK] = 0.0f;
    }
    return;
  }

  // ---- pair scoring + exact stable top-256 via 8-bit radix select on
  // 64-bit keys (score_bits<<32 | pair_idx); set identical to stable argsort.
  // R7: inclusive scan via per-wave __shfl_up (1 barrier) instead of the
  // 16-barrier LDS ladder — these 16 blocks run nearly solo on the GPU.
  {
#pragma clang fp contract(off)
    int b = blk - PREP_BLOCKS;
    int is64 = (z[1] == 0) ? 1 : 0;
    if (t < 64) {
      px[t] = pos[(b * 64 + t) * 3 + 0];
      py[t] = pos[(b * 64 + t) * 3 + 1];
      pz[t] = pos[(b * 64 + t) * 3 + 2];
    }
    if (t == 0) { s_pref = 0; s_K = PSEL; s_done = 0; s_cnt = 0; }
    __syncthreads();
    if (t < 64) {
      float dx = px[t] - px[0], dy = py[t] - py[0], dz = pz[t] - pz[0];
      rr[t] = sqrtf((dx * dx + dy * dy) + dz * dz);
    }
    __syncthreads();
    unsigned long long keys[8];
#pragma unroll
    for (int ii = 0; ii < 8; ii++) {
      int p = t + 256 * ii;
      unsigned long long key = 0xFFFFFFFFFFFFFFFFull;
      if (p < NPAIR) {
        int j, k;
        pair_jk(p, j, k);
        bool vj = (j != 0) && (rr[j] <= 6.0f);
        bool vk = (rr[k] <= 6.0f);
        unsigned int sb = 0x7f800000u;
        if (vj && vk) {
          float dx = px[k] - px[j], dy = py[k] - py[j], dz = pz[k] - pz[j];
          float rjk = sqrtf((dx * dx + dy * dy) + dz * dz);
          float score = (rr[j] + rr[k]) + 0.5f * rjk;
          sb = __float_as_uint(score);
        }
        key = (((unsigned long long)sb) << 32) | (unsigned int)p;
      }
      keys[ii] = key;
    }
    for (int shift = 56; shift >= 0; shift -= 8) {
      if (s_done) break;
      hist[t] = 0;
      __syncthreads();
      unsigned long long hiMask = (shift == 56) ? 0ull : (~0ull << (shift + 8));
      unsigned long long pref = s_pref;
      int K = s_K;
#pragma unroll
      for (int ii = 0; ii < 8; ii++) {
        if ((keys[ii] & hiMask) == pref)
          atomicAdd(&hist[(int)((keys[ii] >> shift) & 255)], 1);
      }
      __syncthreads();
      // inclusive scan of hist[0..255] across bin index t: wave-shfl + combine
      int v = hist[t];
#pragma unroll
      for (int off = 1; off < 64; off <<= 1) {
        int nb = __shfl_up(v, off);
        if ((t & 63) >= off) v += nb;
      }
      if ((t & 63) == 63) scan[t >> 6] = v;  // wave totals in scan[0..3]
      __syncthreads();
      int addw = 0;
#pragma unroll
      for (int ww = 0; ww < 3; ww++)
        if (ww < (t >> 6)) addw += scan[ww];
      int inc = v + addw, exc = inc - hist[t];
      if (exc < K && K <= inc) { s_digit = t; s_exc = exc; }
      __syncthreads();
      int d = s_digit, exc2 = s_exc, cnt = hist[d];
      unsigned long long npref = pref | ((unsigned long long)d << shift);
      if (cnt == 1) {
        unsigned long long inclMask = hiMask | (255ull << shift);
#pragma unroll
        for (int ii = 0; ii < 8; ii++)
          if ((keys[ii] & inclMask) == npref) s_kstar = keys[ii];
        if (t == 0) s_done = 1;
      } else if (shift == 0) {
        if (t == 0) { s_kstar = npref; s_done = 1; }
      } else {
        if (t == 0) { s_pref = npref; s_K = K - exc2; }
      }
      __syncthreads();
    }
    unsigned long long kstar = s_kstar;
#pragma unroll
    for (int ii = 0; ii < 8; ii++) {
      if (keys[ii] <= kstar) {
        int slot = atomicAdd(&s_cnt, 1);
        selk[slot] = keys[ii];
      }
    }
    __syncthreads();
    float myw = 0.0f;
    {
      unsigned long long key = selk[t];
      unsigned int sb = (unsigned int)(key >> 32);
      int p = (int)(key & 0xFFFFFFFFu);
      bool pv = (sb < 0x7f800000u);
      int j = 0, k = 0;
      if (pv) pair_jk(p, j, k);
      float r0j = rr[j], r0k = rr[k];
      float vjx = px[j] - px[0], vjy = py[j] - py[0], vjz = pz[j] - pz[0];
      float vkx = px[k] - px[0], vky = py[k] - py[0], vkz = pz[k] - pz[0];
      float dx = px[k] - px[j], dy = py[k] - py[j], dz = pz[k] - pz[j];
      float rjk = sqrtf((dx * dx + dy * dy) + dz * dz);
      float ij = 1.0f / fmaxf(r0j, 1e-8f);
      float ik = 1.0f / fmaxf(r0k, 1e-8f);
      float cs = (vjx * vkx + vjy * vky + vjz * vkz) * ij * ik;
      cs = fminf(1.0f, fmaxf(-1.0f, cs));
      float w = pv ? (cutf(r0j) * cutf(r0k) * cutf(rjk)) : 0.0f;
      int zj = is64 ? z[(b * 64 + j) * 2] : z[b * 64 + j];
      int zk = is64 ? z[(b * 64 + k) * 2] : z[b * 64 + k];
      int* selJ = (int*)(ws + WS_SELJ);
      int* selK = (int*)(ws + WS_SELK);
      float* scal = (float*)(ws + WS_SCAL);
      selJ[b * PSEL + t] = j;
      selK[b * PSEL + t] = k;
      float* s = &scal[(b * PSEL + t) * 8];
      s[0] = r0j; s[1] = r0k; s[2] = rjk; s[3] = cs; s[4] = w;
      ((int*)s)[5] = zj; ((int*)s)[6] = zk;
      myw = w;
    }
    wred[t] = myw;
    __syncthreads();
    for (int s2 = 128; s2 > 0; s2 >>= 1) {
      if (t < s2) wred[t] += wred[t + s2];
      __syncthreads();
    }
    if (t == 0) ((float*)(ws + WS_SUMW))[b] = fmaxf(wred[0], 1e-8f);
  }
}

// geom MLP via bf16 MFMA: 353(pad384)->256->256->64, folds w/sumw into gg.
// R6: 1024 threads/block. R10: staging remapped wave-per-row — each of the
// 16 waves stages one pair-row with lane-consecutive f, so h reads are 256B
// contiguous per wave-load (was: 16 lanes gathering 16 different h rows).
#define LP3 392
#define LQ3 264
__global__ __launch_bounds__(1024) void k3_geom(const float* __restrict__ h,
    const float* __restrict__ gb0, const float* __restrict__ gb1,
    const float* __restrict__ gb2, char* ws) {
  int blk = blockIdx.x;
  int b = blk >> 4, p0 = (blk & 15) * 16;
  int t = threadIdx.x;
  int lane = t & 63, w = t >> 6;  // w in [0,16)
  int q = lane >> 4, m4 = lane & 15;
  const int* selJ = (const int*)(ws + WS_SELJ);
  const int* selK = (const int*)(ws + WS_SELK);
  const float* scal = (const float*)(ws + WS_SCAL);
  const float* sumw = (const float*)(ws + WS_SUMW);
  float* gg = (float*)(ws + WS_GG);
  const unsigned short* G0F = (const unsigned short*)(ws + WS_G0F);
  const unsigned short* G1F = (const unsigned short*)(ws + WS_G1F);
  const unsigned short* G2F = (const unsigned short*)(ws + WS_G2F);
  __shared__ __align__(16) unsigned short xs[16 * LP3];
  __shared__ __align__(16) unsigned short x1s[16 * LQ3];
  __shared__ __align__(16) unsigned short x2s[16 * LQ3];
  const v4f z4 = {0.f, 0.f, 0.f, 0.f};
  {
    int row = w;  // wave w stages pair-row w; lanes cover f contiguously
    int p = p0 + row;
    int j = selJ[b * PSEL + p], k = selK[b * PSEL + p];
    const float* s = &scal[(b * PSEL + p) * 8];
    float r0j = s[0], r0k = s[1], rjk = s[2], cs = s[3];
    for (int f = lane; f < 384; f += 64) {
      float v;
      if (f < 128) v = h[(b * 64 + j) * 128 + f];
      else if (f < 256) v = h[(b * 64 + k) * 128 + (f - 128)];
      else if (f < 288) v = rbff(r0j, f - 256);
      else if (f < 320) v = rbff(r0k, f - 288);
      else if (f < 352) v = rbff(rjk, f - 320);
      else if (f == 352) v = cs;
      else v = 0.0f;
      xs[row * LP3 + f] = f2bf(v);
    }
  }
  __syncthreads();
  {  // L1: out 16x256, K=384; wave w computes cols [16w, 16w+16)
    v4f acc = z4;
    for (int kk = 0; kk < 12; kk++) {
      v8s bf = *(const v8s*)&xs[m4 * LP3 + 32 * kk + 8 * q];
      v8s wf = *(const v8s*)&G0F[((w * 12 + kk) * 64 + lane) * 8];
      acc = __builtin_amdgcn_mfma_f32_16x16x32_bf16(wf, bf, acc, 0, 0, 0);
    }
    int n0 = 16 * w + 4 * q;
    float4 bias = *(const float4*)&gb0[n0];
    uint2 o;
    o.x = cvt_pk_bf16(siluf_fast(acc[0] + bias.x), siluf_fast(acc[1] + bias.y));
    o.y = cvt_pk_bf16(siluf_fast(acc[2] + bias.z), siluf_fast(acc[3] + bias.w));
    *(uint2*)&x1s[m4 * LQ3 + n0] = o;
  }
  __syncthreads();
  {  // L2: out 16x256, K=256
    v4f acc = z4;
    for (int kk = 0; kk < 8; kk++) {
      v8s bf = *(const v8s*)&x1s[m4 * LQ3 + 32 * kk + 8 * q];
      v8s wf = *(const v8s*)&G1F[((w * 8 + kk) * 64 + lane) * 8];
      acc = __builtin_amdgcn_mfma_f32_16x16x32_bf16(wf, bf, acc, 0, 0, 0);
    }
    int n0 = 16 * w + 4 * q;
    float4 bias = *(const float4*)&gb1[n0];
    uint2 o;
    o.x = cvt_pk_bf16(siluf_fast(acc[0] + bias.x), siluf_fast(acc[1] + bias.y));
    o.y = cvt_pk_bf16(siluf_fast(acc[2] + bias.z), siluf_fast(acc[3] + bias.w));
    *(uint2*)&x2s[m4 * LQ3 + n0] = o;
  }
  __syncthreads();
  if (w < 4) {  // L3: out 16x64, K=256, linear + fold w/norm
    v4f acc = z4;
    for (int kk = 0; kk < 8; kk++) {
      v8s bf = *(const v8s*)&x2s[m4 * LQ3 + 32 * kk + 8 * q];
      v8s wf = *(const v8s*)&G2F[((w * 8 + kk) * 64 + lane) * 8];
      acc = __builtin_amdgcn_mfma_f32_16x16x32_bf16(wf, bf, acc, 0, 0, 0);
    }
    int p = p0 + m4;
    float wp = scal[(b * PSEL + p) * 8 + 4];
    float s2 = wp / sumw[b];
    int n0 = 16 * w + 4 * q;
    float4 bias = *(const float4*)&gb2[n0];
    float4 o;
    o.x = (acc[0] + bias.x) * s2;
    o.y = (acc[1] + bias.y) * s2;
    o.z = (acc[2] + bias.z) * s2;
    o.w = (acc[3] + bias.w) * s2;
    *(float4*)&gg[(b * PSEL + p) * 64 + n0] = o;
  }
}

// fused elem MLP via bf16 MFMA; A0 reconstructed on the fly from zrow tables.
// R10: single dispatch again (R9 split cost ~15us overhead). Body = R7/R8
// best-measured: two LDS buffers, 2 barriers/iter, persistent weight frags,
// bounds(256,4), pc split = 8 (32 pairs/block, g2 loop = 4).
#define LP 136
__global__ __launch_bounds__(256, 4) void k4_elem(
    const float* __restrict__ pb1, const float* __restrict__ pb2, char* ws) {
  int et = blockIdx.x, b = blockIdx.y, pc = blockIdx.z;  // et<16, b<16, pc<8
  int t = threadIdx.x;
  int lane = t & 63, w = t >> 6;
  int q = lane >> 4, m4 = lane & 15;
  const float* Ae = (const float*)(ws + WS_AE);
  const float* gg = (const float*)(ws + WS_GG);
  const float* zrJ = (const float*)(ws + WS_ZRJ);
  const float* zrK = (const float*)(ws + WS_ZRK);
  const unsigned short* W1F = (const unsigned short*)(ws + WS_W1F);
  const unsigned short* W2F = (const unsigned short*)(ws + WS_W2F);
  float* agg = (float*)(ws + WS_AGG);
  __shared__ __align__(16) unsigned short x0s[64 * LP];
  __shared__ __align__(16) unsigned short x1s[64 * LP];
  int e0 = et * 8;

  v8s w1f[2][4], w2f[4];
#pragma unroll
  for (int ct = 0; ct < 2; ct++)
#pragma unroll
    for (int kk = 0; kk < 4; kk++)
      w1f[ct][kk] = *(const v8s*)&W1F[(((2 * w + ct) * 4 + kk) * 64 + lane) * 8];
#pragma unroll
  for (int kk = 0; kk < 4; kk++)
    w2f[kk] = *(const v8s*)&W2F[(((w) * 4 + kk) * 64 + lane) * 8];
  float4 b1v[2];
  b1v[0] = *(const float4*)&pb1[32 * w + 4 * q];
  b1v[1] = *(const float4*)&pb1[32 * w + 16 + 4 * q];
  float4 b2v = *(const float4*)&pb2[16 * w + 4 * q];

  // phase-A constants: thread t covers (pl = t>>5, k0 = (t&31)*4)
  int pl = t >> 5, k0 = (t & 31) * 4;
  const int* sI = (const int*)(ws + WS_SCAL) + (b * PSEL + pc * 32 + pl) * 8;
  const float* aep = Ae + e0 * 128 + k0;
  unsigned short* xw = &x0s[pl * LP + k0];
  const float* ggp = gg + (b * PSEL + pc * 32 + (lane & 7)) * 64 + 16 * w + 4 * q;

  v4f aggR[4];
  v4f gvs;
  const v4f z4 = {0.f, 0.f, 0.f, 0.f};
#pragma unroll
  for (int mt = 0; mt < 4; mt++) aggR[mt] = z4;
  gvs = z4;

  for (int g2 = 0; g2 < 4; g2++) {
    // phase A: x0s[8it+pl][k0..k0+3] = silu(zrJ[zj]+zrK[zk]+Ae[e0+it]), bf16
    int zj = sI[5], zk = sI[6];
    sI += 64;
    float4 aj = *(const float4*)&zrJ[zj * 128 + k0];
    float4 ak = *(const float4*)&zrK[zk * 128 + k0];
    float4 a0v;
    a0v.x = aj.x + ak.x; a0v.y = aj.y + ak.y;
    a0v.z = aj.z + ak.z; a0v.w = aj.w + ak.w;
#pragma unroll
    for (int it = 0; it < 8; it++) {
      float4 aev = *(const float4*)(aep + it * 128);
      uint2 o;
      o.x = cvt_pk_bf16(siluf_fast(a0v.x + aev.x), siluf_fast(a0v.y + aev.y));
      o.y = cvt_pk_bf16(siluf_fast(a0v.z + aev.z), siluf_fast(a0v.w + aev.w));
      *(uint2*)(xw + it * 8 * LP) = o;
    }
    __syncthreads();  // (1) x0 visible; also: all L2-reads of prev iter done
    v4f acc1[4][2];
#pragma unroll
    for (int mt = 0; mt < 4; mt++) { acc1[mt][0] = z4; acc1[mt][1] = z4; }
#pragma unroll
    for (int kk = 0; kk < 4; kk++) {
#pragma unroll
      for (int mt = 0; mt < 4; mt++) {
        v8s bf = *(const v8s*)&x0s[(16 * mt + m4) * LP + 32 * kk + 8 * q];
        acc1[mt][0] = __builtin_amdgcn_mfma_f32_16x16x32_bf16(w1f[0][kk], bf, acc1[mt][0], 0, 0, 0);
        acc1[mt][1] = __builtin_amdgcn_mfma_f32_16x16x32_bf16(w1f[1][kk], bf, acc1[mt][1], 0, 0, 0);
      }
    }
    // x1 writes (no barrier needed: prev-iter L2 reads of x1s ordered before sync (1))
#pragma unroll
    for (int mt = 0; mt < 4; mt++) {
#pragma unroll
      for (int ct = 0; ct < 2; ct++) {
        float4 bias = b1v[ct];
        uint2 o;
        o.x = cvt_pk_bf16(siluf_fast(acc1[mt][ct][0] + bias.x), siluf_fast(acc1[mt][ct][1] + bias.y));
        o.y = cvt_pk_bf16(siluf_fast(acc1[mt][ct][2] + bias.z), siluf_fast(acc1[mt][ct][3] + bias.w));
        int n0 = 32 * w + 16 * ct + 4 * q;
        *(uint2*)&x1s[(16 * mt + m4) * LP + n0] = o;
      }
    }
    __syncthreads();  // (2) x1 visible; also: all L1-reads of x0s done
    v4f acc2[4];
#pragma unroll
    for (int mt = 0; mt < 4; mt++) acc2[mt] = z4;
#pragma unroll
    for (int kk = 0; kk < 4; kk++) {
#pragma unroll
      for (int mt = 0; mt < 4; mt++) {
        v8s bf = *(const v8s*)&x1s[(16 * mt + m4) * LP + 32 * kk + 8 * q];
        acc2[mt] = __builtin_amdgcn_mfma_f32_16x16x32_bf16(w2f[kk], bf, acc2[mt], 0, 0, 0);
      }
    }
    float4 gv = *(const float4*)ggp;
    ggp += 512;
    // bias folded out: sum gv separately, add b2v * (sum gv) after the loop
    gvs[0] += gv.x; gvs[1] += gv.y; gvs[2] += gv.z; gvs[3] += gv.w;
#pragma unroll
    for (int mt = 0; mt < 4; mt++) {
      aggR[mt][0] += gv.x * acc2[mt][0];
      aggR[mt][1] += gv.y * acc2[mt][1];
      aggR[mt][2] += gv.z * acc2[mt][2];
      aggR[mt][3] += gv.w * acc2[mt][3];
    }
  }
#pragma unroll
  for (int mt = 0; mt < 4; mt++) {
    aggR[mt][0] += gvs[0] * b2v.x;
    aggR[mt][1] += gvs[1] * b2v.y;
    aggR[mt][2] += gvs[2] * b2v.z;
    aggR[mt][3] += gvs[3] * b2v.w;
  }
#pragma unroll
  for (int mt = 0; mt < 4; mt++) {
#pragma unroll
    for (int r = 0; r < 4; r++) {
      float v = aggR[mt][r];
      v += __shfl_xor(v, 1);
      v += __shfl_xor(v, 2);
      v += __shfl_xor(v, 4);
      if ((lane & 7) == 0) {
        int e = 2 * mt + ((lane >> 3) & 1);
        int n = 16 * w + 4 * q + r;
        atomicAdd(&agg[(b * NEL + e0 + e) * 64 + n], v);
      }
    }
  }
}

// output MLP 64->256 silu ->128
__global__ __launch_bounds__(256) void k5_out(
    const float* __restrict__ ow0, const float* __restrict__ ob0,
    const float* __restrict__ ow1, const float* __restrict__ ob1,
    const char* ws, float* __restrict__ out) {
  int row0 = blockIdx.x * 16;
  int t = threadIdx.x;
  const float* agg = (const float*)(ws + WS_AGG);
  __shared__ float xT[64][16];
  __shared__ float x1T[256][16];
  {
    int row = t & 15, fs = t >> 4;
    for (int f = fs; f < 64; f += 16) xT[f][row] = agg[(row0 + row) * 64 + f];
  }
  __syncthreads();
  {
    int r0 = (t & 3) * 4, c0 = (t >> 2) * 4;
    float acc[4][4] = {};
    for (int k2 = 0; k2 < 64; k2++) {
      float4 xv = *(const float4*)&xT[k2][r0];
      float4 wv = *(const float4*)&ow0[k2 * 256 + c0];
      float xs2[4] = {xv.x, xv.y, xv.z, xv.w};
      float wss[4] = {wv.x, wv.y, wv.z, wv.w};
#pragma unroll
      for (int i = 0; i < 4; i++)
#pragma unroll
        for (int j2 = 0; j2 < 4; j2++) acc[i][j2] += xs2[i] * wss[j2];
    }
#pragma unroll
    for (int jj = 0; jj < 4; jj++) {
      float bias = ob0[c0 + jj];
#pragma unroll
      for (int i = 0; i < 4; i++) x1T[c0 + jj][r0 + i] = siluf_fast(acc[i][jj] + bias);
    }
  }
  __syncthreads();
  {
    int r0 = (t & 3) * 4, c0 = (t >> 2) * 2;
    float acc[4][2] = {};
    for (int k2 = 0; k2 < 256; k2++) {
      float4 xv = *(const float4*)&x1T[k2][r0];
      float2 wv = *(const float2*)&ow1[k2 * 128 + c0];
      float xs2[4] = {xv.x, xv.y, xv.z, xv.w};
#pragma unroll
      for (int i = 0; i < 4; i++) {
        acc[i][0] += xs2[i] * wv.x;
        acc[i][1] += xs2[i] * wv.y;
      }
    }
#pragma unroll
    for (int i = 0; i < 4; i++)
#pragma unroll
      for (int j2 = 0; j2 < 2; j2++)
        out[(row0 + r0 + i) * 128 + c0 + j2] = acc[i][j2] + ob1[c0 + j2];
  }
}

extern "C" void kernel_launch(void* const* d_in, const int* in_sizes, int n_in,
                              void* d_out, int out_size, void* d_ws, size_t ws_size,
                              hipStream_t stream) {
  const float* h     = (const float*)d_in[0];
  const int*   z     = (const int*)d_in[1];
  const float* pos   = (const float*)d_in[2];
  const float* efeat = (const float*)d_in[4];
  const float* zemb  = (const float*)d_in[5];
  const float* pw0 = (const float*)d_in[6];
  const float* pb0 = (const float*)d_in[7];
  const float* pw1 = (const float*)d_in[8];
  const float* pb1 = (const float*)d_in[9];
  const float* pw2 = (const float*)d_in[10];
  const float* pb2 = (const float*)d_in[11];
  const float* gw0 = (const float*)d_in[12];
  const float* gb0 = (const float*)d_in[13];
  const float* gw1 = (const float*)d_in[14];
  const float* gb1 = (const float*)d_in[15];
  const float* gw2 = (const float*)d_in[16];
  const float* gb2 = (const float*)d_in[17];
  const float* ow0 = (const float*)d_in[18];
  const float* ob0 = (const float*)d_in[19];
  const float* ow1 = (const float*)d_in[20];
  const float* ob1 = (const float*)d_in[21];
  char* ws = (char*)d_ws;
  float* out = (float*)d_out;

  kA<<<PREP_BLOCKS + 16, 256, 0, stream>>>(z, efeat, pos, pw0, pb0, pw1, pw2,
                                           gw0, gw1, gw2, zemb, ws);
  k3_geom<<<256, 1024, 0, stream>>>(h, gb0, gb1, gb2, ws);
  k4_elem<<<dim3(16, 16, 8), 256, 0, stream>>>(pb1, pb2, ws);
  k5_out<<<128, 256, 0, stream>>>(ow0, ob0, ow1, ob1, ws, out);
}